// Round 7
// baseline (750.354 us; speedup 1.0000x reference)
//
#include <hip/hip_runtime.h>
#include <cstdint>

#define P 7
#define PP 49
#define IMG 64
#define PIX 4096
#define XSTR 71    // LDS tile row stride (odd -> 2-way bank aliasing, free)
#define XROWS 28   // xs tile rows: x rows q*16-6 .. q*16+21
#define MROWS 22   // ms tile rows: maps1 rows q*16-3 .. q*16+18

// ---- 7x8 window in 56 named scalars (no arrays -> no scratch) ----
#define DECLW \
    float x00,x01,x02,x03,x04,x05,x06,x07; \
    float x10,x11,x12,x13,x14,x15,x16,x17; \
    float x20,x21,x22,x23,x24,x25,x26,x27; \
    float x30,x31,x32,x33,x34,x35,x36,x37; \
    float x40,x41,x42,x43,x44,x45,x46,x47; \
    float x50,x51,x52,x53,x54,x55,x56,x57; \
    float x60,x61,x62,x63,x64,x65,x66,x67;

#define LDROW(i, BP) \
    x##i##0=(BP)[0]; x##i##1=(BP)[1]; x##i##2=(BP)[2]; x##i##3=(BP)[3]; \
    x##i##4=(BP)[4]; x##i##5=(BP)[5]; x##i##6=(BP)[6]; x##i##7=(BP)[7];

#define LDWIN(B) \
    LDROW(0,(B)+0*XSTR) LDROW(1,(B)+1*XSTR) LDROW(2,(B)+2*XSTR) \
    LDROW(3,(B)+3*XSTR) LDROW(4,(B)+4*XSTR) LDROW(5,(B)+5*XSTR) \
    LDROW(6,(B)+6*XSTR)

// per-row window sums: px0 uses cols 0..6, px1 uses 1..7, each k-ascending
#define SUMROW(i) \
    s0+=x##i##0; s1+=x##i##1; s0+=x##i##1; s1+=x##i##2; \
    s0+=x##i##2; s1+=x##i##3; s0+=x##i##3; s1+=x##i##4; \
    s0+=x##i##4; s1+=x##i##5; s0+=x##i##5; s1+=x##i##6; \
    s0+=x##i##6; s1+=x##i##7;

#define SUMALL SUMROW(0) SUMROW(1) SUMROW(2) SUMROW(3) SUMROW(4) SUMROW(5) SUMROW(6)

// ---- stage 1: one filter (weights from LDS broadcast), 2 px ----
#define S1TAP(i,j,jp) { const float w = w1s[(i)*7+(j)]; \
    a0 = fmaf(w, x##i##j - mu0, a0); b0 = fmaf(w, x##i##jp - mu1, b0); }
#define S1ROW(i) \
    S1TAP(i,0,1) S1TAP(i,1,2) S1TAP(i,2,3) S1TAP(i,3,4) \
    S1TAP(i,4,5) S1TAP(i,5,6) S1TAP(i,6,7)
#define S1ALL S1ROW(0) S1ROW(1) S1ROW(2) S1ROW(3) S1ROW(4) S1ROW(5) S1ROW(6)

// ---- stage 2: 8 filters via two ds_read_b128 broadcasts per tap, 2 px ----
// fmaf order identical to verified rounds: f ascending, (a_f, b_f) pairs.
#define S2TAP(i,j,jp) { \
    const float t0 = x##i##j - mu0, t1 = x##i##jp - mu1; \
    const float4 wA = *(const float4*)&w2s[((i)*7+(j))*8]; \
    const float4 wB = *(const float4*)&w2s[((i)*7+(j))*8 + 4]; \
    a0=fmaf(wA.x,t0,a0); b0=fmaf(wA.x,t1,b0); \
    a1=fmaf(wA.y,t0,a1); b1=fmaf(wA.y,t1,b1); \
    a2=fmaf(wA.z,t0,a2); b2=fmaf(wA.z,t1,b2); \
    a3=fmaf(wA.w,t0,a3); b3=fmaf(wA.w,t1,b3); \
    a4=fmaf(wB.x,t0,a4); b4=fmaf(wB.x,t1,b4); \
    a5=fmaf(wB.y,t0,a5); b5=fmaf(wB.y,t1,b5); \
    a6=fmaf(wB.z,t0,a6); b6=fmaf(wB.z,t1,b6); \
    a7=fmaf(wB.w,t0,a7); b7=fmaf(wB.w,t1,b7); }
#define S2ROW(i) \
    S2TAP(i,0,1) S2TAP(i,1,2) S2TAP(i,2,3) S2TAP(i,3,4) \
    S2TAP(i,4,5) S2TAP(i,5,6) S2TAP(i,6,7)
#define S2ALL S2ROW(0) S2ROW(1) S2ROW(2) S2ROW(3) S2ROW(4) S2ROW(5) S2ROW(6)

// ---------------------------------------------------------------------------
// One block per (channel, row-quarter): 2048 blocks x 256 threads.
// Window held in 56 named registers (loaded once); weights broadcast from
// LDS (no s_load streaming, no SGPR rotation). launch_bounds(256,3) gives
// ~168-VGPR cap so the ~100-reg live set fits without remat/spill.
// Per-pixel op order bit-identical to the verified rounds.
// ---------------------------------------------------------------------------
__global__ __launch_bounds__(256, 3) void stage_kernel(
    const float* __restrict__ x,    // [64][64][64]
    const float* __restrict__ W1,   // [49][8]
    const float* __restrict__ W2,   // [49][8]
    uint8_t* __restrict__ codes)    // [512][4096]
{
    __shared__ float xs[XROWS * XSTR];  // x rows q16-6 .. q16+21, cols -3..67
    __shared__ float ms[MROWS * XSTR];  // maps1 rows q16-3 .. q16+18, cols -3..67
    __shared__ float w1s[PP];
    __shared__ __align__(16) float w2s[PP * 8];

    const int b    = blockIdx.x;
    const int ch   = b >> 2;
    const int q16  = (b & 3) * 16;
    const int l    = ch >> 6;
    const int img  = ch & 63;
    const int tid  = threadIdx.x;

    // stage weights into LDS
    if (tid < PP) w1s[tid] = W1[tid * 8 + l];
    #pragma unroll 1
    for (int i = tid; i < PP * 8; i += 256) w2s[i] = W2[i];

    // zero ms (stage-2 SAME padding: pad cols + out-of-image rows stay 0)
    #pragma unroll 1
    for (int i = tid; i < MROWS * XSTR; i += 256) ms[i] = 0.f;

    // load xs zero-padded
    const float* xb = x + (size_t)img * PIX;
    #pragma unroll 1
    for (int idx = tid; idx < XROWS * XSTR; idx += 256) {
        int r  = idx / XSTR, c = idx - r * XSTR;
        int gr = q16 - 6 + r, gc = c - 3;
        float v = 0.f;
        if (gr >= 0 && gr < IMG && gc >= 0 && gc < IMG)
            v = xb[gr * IMG + gc];
        xs[idx] = v;
    }
    __syncthreads();

    // ---- stage 1: 22 rows x 32 col-strips = 704 strips ----
    #pragma unroll 1
    for (int it = 0; it < 3; ++it) {
        int s = tid + it * 256;
        if (s < MROWS * 32) {
            const int row = s >> 5;           // 0..21
            const int cs2 = (s & 31) * 2;     // 0..62
            const float* bp = &xs[row * XSTR + cs2];
            DECLW
            LDWIN(bp)
            float s0 = 0.f, s1 = 0.f;
            SUMALL
            const float mu0 = s0 / 49.0f, mu1 = s1 / 49.0f;
            float a0 = 0.f, b0 = 0.f;
            S1ALL
            const int gm = q16 - 3 + row;
            const bool in_img = (gm >= 0) && (gm < IMG);
            float* mp = &ms[row * XSTR + 3 + cs2];
            mp[0] = in_img ? a0 : 0.f;
            mp[1] = in_img ? b0 : 0.f;
        }
    }
    __syncthreads();

    // ---- stage 2 + code bits: 16 rows x 32 col-strips = 512 strips ----
    uint8_t* cg = codes + (size_t)ch * PIX;
    #pragma unroll 1
    for (int it = 0; it < 2; ++it) {
        int s = tid + it * 256;
        const int rr  = s >> 5;               // 0..15
        const int cs2 = (s & 31) * 2;         // 0..62
        const float* bp = &ms[rr * XSTR + cs2];
        DECLW
        LDWIN(bp)
        float s0 = 0.f, s1 = 0.f;
        SUMALL
        const float mu0 = s0 / 49.0f, mu1 = s1 / 49.0f;
        float a0=0.f,a1=0.f,a2=0.f,a3=0.f,a4=0.f,a5=0.f,a6=0.f,a7=0.f;
        float b0=0.f,b1=0.f,b2=0.f,b3=0.f,b4=0.f,b5=0.f,b6=0.f,b7=0.f;
        S2ALL
        uint32_t c0 = 0, c1 = 0;
        c0 |= (a0>0.f)?128u:0u; c1 |= (b0>0.f)?128u:0u;
        c0 |= (a1>0.f)? 64u:0u; c1 |= (b1>0.f)? 64u:0u;
        c0 |= (a2>0.f)? 32u:0u; c1 |= (b2>0.f)? 32u:0u;
        c0 |= (a3>0.f)? 16u:0u; c1 |= (b3>0.f)? 16u:0u;
        c0 |= (a4>0.f)?  8u:0u; c1 |= (b4>0.f)?  8u:0u;
        c0 |= (a5>0.f)?  4u:0u; c1 |= (b5>0.f)?  4u:0u;
        c0 |= (a6>0.f)?  2u:0u; c1 |= (b6>0.f)?  2u:0u;
        c0 |= (a7>0.f)?  1u:0u; c1 |= (b7>0.f)?  1u:0u;
        *(uint16_t*)(cg + (q16 + rr) * 64 + cs2) = (uint16_t)(c0 | (c1 << 8));
    }
}

// ---------------------------------------------------------------------------
// Kernel B: histogram + entropy (unchanged, ~5 us)
// ---------------------------------------------------------------------------
#define CPB 32

__global__ __launch_bounds__(256) void hist_kernel(
    const uint8_t* __restrict__ codes,  // [512][4096]
    float* __restrict__ out)            // [49*256][512]
{
    __shared__ uint32_t hist[256 * 33];

    const int bid   = blockIdx.x;       // 0..783
    const int cgrp  = bid & 15;
    const int nb    = bid >> 4;         // 0..48
    const int bi    = nb / 7, bj = nb - bi * 7;
    const int tid   = threadIdx.x;
    const int cbase = cgrp * CPB;

    for (int i = tid; i < 256 * 33; i += 256) hist[i] = 0;
    __syncthreads();

    const int cl  = tid >> 3;           // 0..31
    const int sub = tid & 7;            // 0..7
    const uint8_t* cp = codes + (size_t)(cbase + cl) * PIX;
    #pragma unroll
    for (int rr = 0; rr < 2; ++rr) {
        int row = bi * 8 + (sub * 2 + rr);
        const uint8_t* rp = cp + row * 64 + bj * 8;
        uint64_t v0 = *(const uint64_t*)(rp);
        uint64_t v1 = *(const uint64_t*)(rp + 8);
        #pragma unroll
        for (int t = 0; t < 8; ++t)
            atomicAdd(&hist[(uint32_t)((v0 >> (8 * t)) & 255u) * 33 + cl], 1u);
        #pragma unroll
        for (int t = 0; t < 8; ++t)
            atomicAdd(&hist[(uint32_t)((v1 >> (8 * t)) & 255u) * 33 + cl], 1u);
    }
    __syncthreads();

    const int lane_c = tid & 31;
    const int bin0   = tid >> 5;        // 0..7
    for (int i = 0; i < 32; ++i) {
        int bin = i * 8 + bin0;
        uint32_t cnt = hist[bin * 33 + lane_c];
        float ent = 0.f;
        if (cnt > 0) {
            float pz = (float)cnt * (1.0f / 256.0f);
            ent = -pz * log2f(pz);
        }
        out[((size_t)(nb * 256 + bin)) * 512 + cbase + lane_c] = ent;
    }
}

extern "C" void kernel_launch(void* const* d_in, const int* in_sizes, int n_in,
                              void* d_out, int out_size, void* d_ws, size_t ws_size,
                              hipStream_t stream) {
    const float* x  = (const float*)d_in[0];
    const float* W1 = (const float*)d_in[1];
    const float* W2 = (const float*)d_in[2];
    float* out = (float*)d_out;
    uint8_t* codes = (uint8_t*)d_ws;   // 512*4096 = 2 MB

    stage_kernel<<<2048, 256, 0, stream>>>(x, W1, W2, codes);
    hist_kernel<<<784, 256, 0, stream>>>(codes, out);
}

// Round 9
// 65.313 us; speedup vs baseline: 11.4886x; 11.4886x over previous
//
#include <hip/hip_runtime.h>
#include <cstdint>

#define P 7
#define PP 49
#define IMG 64
#define PIX 4096
#define XSTR 71    // LDS tile row stride (odd -> 2-way bank aliasing, free)
#define XROWS 28   // xs tile rows: x rows q*16-6 .. q*16+21
#define MROWS 22   // ms tile rows: maps1 rows q*16-3 .. q*16+18

// ---- 7x8 window in 56 named scalars (no arrays -> no scratch) ----
#define DECLW \
    float x00,x01,x02,x03,x04,x05,x06,x07; \
    float x10,x11,x12,x13,x14,x15,x16,x17; \
    float x20,x21,x22,x23,x24,x25,x26,x27; \
    float x30,x31,x32,x33,x34,x35,x36,x37; \
    float x40,x41,x42,x43,x44,x45,x46,x47; \
    float x50,x51,x52,x53,x54,x55,x56,x57; \
    float x60,x61,x62,x63,x64,x65,x66,x67;

#define LDROW(i, BP) \
    x##i##0=(BP)[0]; x##i##1=(BP)[1]; x##i##2=(BP)[2]; x##i##3=(BP)[3]; \
    x##i##4=(BP)[4]; x##i##5=(BP)[5]; x##i##6=(BP)[6]; x##i##7=(BP)[7];

#define LDWIN(B) \
    LDROW(0,(B)+0*XSTR) LDROW(1,(B)+1*XSTR) LDROW(2,(B)+2*XSTR) \
    LDROW(3,(B)+3*XSTR) LDROW(4,(B)+4*XSTR) LDROW(5,(B)+5*XSTR) \
    LDROW(6,(B)+6*XSTR)

// per-row window sums: px0 uses cols 0..6, px1 uses 1..7, each k-ascending
#define SUMROW(i) \
    s0+=x##i##0; s1+=x##i##1; s0+=x##i##1; s1+=x##i##2; \
    s0+=x##i##2; s1+=x##i##3; s0+=x##i##3; s1+=x##i##4; \
    s0+=x##i##4; s1+=x##i##5; s0+=x##i##5; s1+=x##i##6; \
    s0+=x##i##6; s1+=x##i##7;

#define SUMALL SUMROW(0) SUMROW(1) SUMROW(2) SUMROW(3) SUMROW(4) SUMROW(5) SUMROW(6)

// ---- stage 1: one filter, weights broadcast from LDS; fence per tap ----
// sched_barrier(0x3): only ALU/VALU may cross -> ds_reads stay pinned to
// their tap (bounded weight liveness; prevents the r7 hoist->spill), while
// fmas may still move to hide DS latency.
#define S1TAP(i,j,jp) { const float w = w1s[(i)*7+(j)]; \
    a0 = fmaf(w, x##i##j - mu0, a0); b0 = fmaf(w, x##i##jp - mu1, b0); \
    __builtin_amdgcn_sched_barrier(0x3); }
#define S1ROW(i) \
    S1TAP(i,0,1) S1TAP(i,1,2) S1TAP(i,2,3) S1TAP(i,3,4) \
    S1TAP(i,4,5) S1TAP(i,5,6) S1TAP(i,6,7)
#define S1ALL S1ROW(0) S1ROW(1) S1ROW(2) S1ROW(3) S1ROW(4) S1ROW(5) S1ROW(6)

// ---- stage 2: 8 filters via two 16B LDS broadcasts per tap; fence per tap --
// fmaf order identical to verified rounds: f ascending, (a_f, b_f) pairs.
#define S2TAP(i,j,jp) { \
    const float t0 = x##i##j - mu0, t1 = x##i##jp - mu1; \
    const float4 wA = *(const float4*)&w2s[((i)*7+(j))*8]; \
    const float4 wB = *(const float4*)&w2s[((i)*7+(j))*8 + 4]; \
    a0=fmaf(wA.x,t0,a0); b0=fmaf(wA.x,t1,b0); \
    a1=fmaf(wA.y,t0,a1); b1=fmaf(wA.y,t1,b1); \
    a2=fmaf(wA.z,t0,a2); b2=fmaf(wA.z,t1,b2); \
    a3=fmaf(wA.w,t0,a3); b3=fmaf(wA.w,t1,b3); \
    a4=fmaf(wB.x,t0,a4); b4=fmaf(wB.x,t1,b4); \
    a5=fmaf(wB.y,t0,a5); b5=fmaf(wB.y,t1,b5); \
    a6=fmaf(wB.z,t0,a6); b6=fmaf(wB.z,t1,b6); \
    a7=fmaf(wB.w,t0,a7); b7=fmaf(wB.w,t1,b7); \
    __builtin_amdgcn_sched_barrier(0x3); }
#define S2ROW(i) \
    S2TAP(i,0,1) S2TAP(i,1,2) S2TAP(i,2,3) S2TAP(i,3,4) \
    S2TAP(i,4,5) S2TAP(i,5,6) S2TAP(i,6,7)
#define S2ALL S2ROW(0) S2ROW(1) S2ROW(2) S2ROW(3) S2ROW(4) S2ROW(5) S2ROW(6)

// ---------------------------------------------------------------------------
// One block per (channel, row-quarter): 2048 blocks x 256 threads.
// r6 structure; single change vs r6: weights broadcast from LDS instead of
// streamed s_loads, with per-tap sched fences bounding weight liveness.
// (r8's bug fixed: w2s staged by ALL 256 threads, covering all 392 floats.)
// Per-pixel op order bit-identical to the verified rounds.
// ---------------------------------------------------------------------------
__global__ __launch_bounds__(256, 4) void stage_kernel(
    const float* __restrict__ x,    // [64][64][64]
    const float* __restrict__ W1,   // [49][8]
    const float* __restrict__ W2,   // [49][8]
    uint8_t* __restrict__ codes)    // [512][4096]
{
    __shared__ float xs[XROWS * XSTR];  // x rows q16-6 .. q16+21, cols -3..67
    __shared__ float ms[MROWS * XSTR];  // maps1 rows q16-3 .. q16+18, cols -3..67
    __shared__ float w1s[PP];
    __shared__ __align__(16) float w2s[PP * 8];

    const int b    = blockIdx.x;
    const int ch   = b >> 2;
    const int q16  = (b & 3) * 16;
    const int l    = ch >> 6;
    const int img  = ch & 63;
    const int tid  = threadIdx.x;

    // stage weights into LDS (all threads cover all elements)
    if (tid < PP) w1s[tid] = W1[tid * 8 + l];
    #pragma unroll 1
    for (int i = tid; i < PP * 8; i += 256) w2s[i] = W2[i];

    // zero ms (stage-2 SAME padding: pad cols + out-of-image rows stay 0)
    #pragma unroll 1
    for (int i = tid; i < MROWS * XSTR; i += 256) ms[i] = 0.f;

    // load xs zero-padded
    const float* xb = x + (size_t)img * PIX;
    #pragma unroll 1
    for (int idx = tid; idx < XROWS * XSTR; idx += 256) {
        int r  = idx / XSTR, c = idx - r * XSTR;
        int gr = q16 - 6 + r, gc = c - 3;
        float v = 0.f;
        if (gr >= 0 && gr < IMG && gc >= 0 && gc < IMG)
            v = xb[gr * IMG + gc];
        xs[idx] = v;
    }
    __syncthreads();

    // ---- stage 1: 22 rows x 32 col-strips = 704 strips ----
    #pragma unroll 1
    for (int it = 0; it < 3; ++it) {
        int s = tid + it * 256;
        if (s < MROWS * 32) {
            const int row = s >> 5;           // 0..21
            const int cs2 = (s & 31) * 2;     // 0..62
            const float* bp = &xs[row * XSTR + cs2];
            DECLW
            LDWIN(bp)
            float s0 = 0.f, s1 = 0.f;
            SUMALL
            const float mu0 = s0 / 49.0f, mu1 = s1 / 49.0f;
            float a0 = 0.f, b0 = 0.f;
            S1ALL
            const int gm = q16 - 3 + row;
            const bool in_img = (gm >= 0) && (gm < IMG);
            float* mp = &ms[row * XSTR + 3 + cs2];
            mp[0] = in_img ? a0 : 0.f;
            mp[1] = in_img ? b0 : 0.f;
        }
    }
    __syncthreads();

    // ---- stage 2 + code bits: 16 rows x 32 col-strips = 512 strips ----
    uint8_t* cg = codes + (size_t)ch * PIX;
    #pragma unroll 1
    for (int it = 0; it < 2; ++it) {
        int s = tid + it * 256;
        const int rr  = s >> 5;               // 0..15
        const int cs2 = (s & 31) * 2;         // 0..62
        const float* bp = &ms[rr * XSTR + cs2];
        DECLW
        LDWIN(bp)
        float s0 = 0.f, s1 = 0.f;
        SUMALL
        const float mu0 = s0 / 49.0f, mu1 = s1 / 49.0f;
        float a0=0.f,a1=0.f,a2=0.f,a3=0.f,a4=0.f,a5=0.f,a6=0.f,a7=0.f;
        float b0=0.f,b1=0.f,b2=0.f,b3=0.f,b4=0.f,b5=0.f,b6=0.f,b7=0.f;
        S2ALL
        uint32_t c0 = 0, c1 = 0;
        c0 |= (a0>0.f)?128u:0u; c1 |= (b0>0.f)?128u:0u;
        c0 |= (a1>0.f)? 64u:0u; c1 |= (b1>0.f)? 64u:0u;
        c0 |= (a2>0.f)? 32u:0u; c1 |= (b2>0.f)? 32u:0u;
        c0 |= (a3>0.f)? 16u:0u; c1 |= (b3>0.f)? 16u:0u;
        c0 |= (a4>0.f)?  8u:0u; c1 |= (b4>0.f)?  8u:0u;
        c0 |= (a5>0.f)?  4u:0u; c1 |= (b5>0.f)?  4u:0u;
        c0 |= (a6>0.f)?  2u:0u; c1 |= (b6>0.f)?  2u:0u;
        c0 |= (a7>0.f)?  1u:0u; c1 |= (b7>0.f)?  1u:0u;
        *(uint16_t*)(cg + (q16 + rr) * 64 + cs2) = (uint16_t)(c0 | (c1 << 8));
    }
}

// ---------------------------------------------------------------------------
// Kernel B: histogram + entropy (unchanged, ~5 us)
// ---------------------------------------------------------------------------
#define CPB 32

__global__ __launch_bounds__(256) void hist_kernel(
    const uint8_t* __restrict__ codes,  // [512][4096]
    float* __restrict__ out)            // [49*256][512]
{
    __shared__ uint32_t hist[256 * 33];

    const int bid   = blockIdx.x;       // 0..783
    const int cgrp  = bid & 15;
    const int nb    = bid >> 4;         // 0..48
    const int bi    = nb / 7, bj = nb - bi * 7;
    const int tid   = threadIdx.x;
    const int cbase = cgrp * CPB;

    for (int i = tid; i < 256 * 33; i += 256) hist[i] = 0;
    __syncthreads();

    const int cl  = tid >> 3;           // 0..31
    const int sub = tid & 7;            // 0..7
    const uint8_t* cp = codes + (size_t)(cbase + cl) * PIX;
    #pragma unroll
    for (int rr = 0; rr < 2; ++rr) {
        int row = bi * 8 + (sub * 2 + rr);
        const uint8_t* rp = cp + row * 64 + bj * 8;
        uint64_t v0 = *(const uint64_t*)(rp);
        uint64_t v1 = *(const uint64_t*)(rp + 8);
        #pragma unroll
        for (int t = 0; t < 8; ++t)
            atomicAdd(&hist[(uint32_t)((v0 >> (8 * t)) & 255u) * 33 + cl], 1u);
        #pragma unroll
        for (int t = 0; t < 8; ++t)
            atomicAdd(&hist[(uint32_t)((v1 >> (8 * t)) & 255u) * 33 + cl], 1u);
    }
    __syncthreads();

    const int lane_c = tid & 31;
    const int bin0   = tid >> 5;        // 0..7
    for (int i = 0; i < 32; ++i) {
        int bin = i * 8 + bin0;
        uint32_t cnt = hist[bin * 33 + lane_c];
        float ent = 0.f;
        if (cnt > 0) {
            float pz = (float)cnt * (1.0f / 256.0f);
            ent = -pz * log2f(pz);
        }
        out[((size_t)(nb * 256 + bin)) * 512 + cbase + lane_c] = ent;
    }
}

extern "C" void kernel_launch(void* const* d_in, const int* in_sizes, int n_in,
                              void* d_out, int out_size, void* d_ws, size_t ws_size,
                              hipStream_t stream) {
    const float* x  = (const float*)d_in[0];
    const float* W1 = (const float*)d_in[1];
    const float* W2 = (const float*)d_in[2];
    float* out = (float*)d_out;
    uint8_t* codes = (uint8_t*)d_ws;   // 512*4096 = 2 MB

    stage_kernel<<<2048, 256, 0, stream>>>(x, W1, W2, codes);
    hist_kernel<<<784, 256, 0, stream>>>(codes, out);
}